// Round 12
// baseline (480.465 us; speedup 1.0000x reference)
//
#include <hip/hip_runtime.h>
#include <hip/hip_bf16.h>

#define NN 50000
#define NE 400000
#define WTP 136   // padded LDS row (elems): 272B = 17*16B -> 2-way banks, 16B aligned

// ---- workspace layout (bytes) ----
static const size_t OFF_ALPHA  = 0;                       // [NE,4]  f32 =  6,400,000
static const size_t OFF_SEGSUM = 6400000;                 // [NN,4]  f32 =    800,000
static const size_t OFF_BN     = 7200000;                 // 16 f32 + flag =      256
static const size_t OFF_AGGR   = 7200256;                 // 4x[NN,64] f32 = 51,200,000
static const size_t OFF_IDX32  = 58400256;                // [2,NE]  i32 =  3,200,000
static const size_t OFF_WT     = 61600256;                // [256,128] bf16 =  65,536
static const size_t OFF_XB     = 61665792;                // [NN,64] bf16 =  6,400,000
static const size_t OFF_EAB    = 68065792;                // [NE,64] bf16 = 51,200,000
static const size_t Z_SZ       = OFF_IDX32 - OFF_SEGSUM;  // segsum+bn+aggr(x4) zeroed

typedef __attribute__((ext_vector_type(8))) __bf16 bf16x8;
typedef __attribute__((ext_vector_type(4))) float  f32x4;
typedef __attribute__((ext_vector_type(4))) int    i32x4;
typedef __attribute__((ext_vector_type(2))) unsigned u32x2;

#define L2E 1.44269504f
#define LN2 0.69314718f

__device__ __forceinline__ float fexp2(float x) {
  float r; asm("v_exp_f32 %0, %1" : "=v"(r) : "v"(x)); return r;
}
__device__ __forceinline__ float flog2(float x) {
  float r; asm("v_log_f32 %0, %1" : "=v"(r) : "v"(x)); return r;
}
__device__ __forceinline__ float softplusf(float x) {
  return fmaxf(x, 0.0f) + LN2 * flog2(1.0f + fexp2(-L2E * fabsf(x)));
}
__device__ __forceinline__ float expsp(float y) {
  return fexp2(L2E * fmaxf(y, 0.0f)) * (1.0f + fexp2(-L2E * fabsf(y)));
}
__device__ __forceinline__ unsigned bfbits(float f) {
  return (unsigned)__builtin_bit_cast(unsigned short, __float2bfloat16(f));
}
__device__ __forceinline__ unsigned pkbf(float a, float b) {
  return bfbits(a) | (bfbits(b) << 16);
}
__device__ __forceinline__ bf16x8 ld8(const unsigned short* p) {
  return __builtin_bit_cast(bf16x8, *reinterpret_cast<const i32x4*>(p));
}
#define MFMA __builtin_amdgcn_mfma_f32_16x16x32_bf16

// ---------- idx dtype detect + convert ----------
__global__ __launch_bounds__(256)
void k_idx_detect(const unsigned* __restrict__ src, unsigned* __restrict__ flag)
{
  int t = blockIdx.x * 256 + threadIdx.x;
  unsigned v = (t < NE) ? src[2 * t + 1] : 0u;
  if (__any(v != 0)) { if ((threadIdx.x & 63) == 0) atomicOr(flag, 1u); }
}
__global__ __launch_bounds__(256)
void k_idx_cvt(const unsigned* __restrict__ src, const unsigned* __restrict__ flag,
               int* __restrict__ dst)
{
  int e = blockIdx.x * 256 + threadIdx.x;
  unsigned f = *flag;
  dst[e] = (int)(f ? src[e] : src[2 * e]);
}

// ---------- Wt[c][k] = bf16(W[k][c]), [256 cols][128 k] = 64KB ----------
__global__ __launch_bounds__(256)
void k_wprep(const float* __restrict__ W, __hip_bfloat16* __restrict__ wt)
{
  int t = blockIdx.x * 256 + threadIdx.x;
  int k = t >> 8, c = t & 255;
  wt[c * 128 + k] = __float2bfloat16(W[t]);
}

// ---------- f32 -> bf16 bulk convert ----------
__global__ __launch_bounds__(256)
void k_cvt_bf16(const float* __restrict__ src, unsigned* __restrict__ dst)
{
  int t = blockIdx.x * 256 + threadIdx.x;
  f32x4 v = *reinterpret_cast<const f32x4*>(src + (size_t)t * 4);
  u32x2 p = { pkbf(v[0], v[1]), pkbf(v[2], v[3]) };
  *reinterpret_cast<u32x2*>(dst + (size_t)t * 2) = p;
}

// ---------- stage wt into padded LDS (both edge kernels) ----------
__device__ __forceinline__ void stage_wt(unsigned short* wtl,
                                         const unsigned short* wtu, int tid)
{
  for (int it = tid; it < 4096; it += 512) {           // 4096 * 16B = 64KB
    int c = it >> 4, k8 = (it & 15) << 3;
    *reinterpret_cast<i32x4*>(&wtl[c * WTP + k8]) =
        *reinterpret_cast<const i32x4*>(wtu + c * 128 + k8);
  }
}

// ---------- pass 1: [x,ea]@W via MFMA; 32 edges/wave, wt in LDS ----------
__global__ __launch_bounds__(512, 2)
void k_edge_alpha(const __hip_bfloat16* __restrict__ xb,
                  const __hip_bfloat16* __restrict__ eab,
                  const __hip_bfloat16* __restrict__ wt,
                  const float* __restrict__ att, const int* __restrict__ idx,
                  float* __restrict__ alpha, float* __restrict__ bnst)
{
  __shared__ __align__(16) unsigned short wtl[256 * WTP];
  __shared__ float attl[512];
  __shared__ float red[64];
  const unsigned short* wtu = reinterpret_cast<const unsigned short*>(wt);
  stage_wt(wtl, wtu, threadIdx.x);
  if (threadIdx.x < 512) attl[threadIdx.x] = att[threadIdx.x];
  __syncthreads();

  const int wave = threadIdx.x >> 6, lane = threadIdx.x & 63;
  const int m = lane & 15, rg = lane >> 4;
  const unsigned short* xbu = reinterpret_cast<const unsigned short*>(xb);
  const unsigned short* eau = reinterpret_cast<const unsigned short*>(eab);
  const int e0r = blockIdx.x * 256 + wave * 32;
  const bool oob = (e0r >= NE);          // wave-uniform (NE % 32 == 0)
  const int e0 = oob ? 0 : e0r;

  const int iA = idx[e0 + m],      jA = idx[NE + e0 + m];
  const int iB = idx[e0 + 16 + m], jB = idx[NE + e0 + 16 + m];
  bf16x8 xiA0 = ld8(xbu + (size_t)iA * 64 + rg * 8);
  bf16x8 xiA1 = ld8(xbu + (size_t)iA * 64 + 32 + rg * 8);
  bf16x8 xjA0 = ld8(xbu + (size_t)jA * 64 + rg * 8);
  bf16x8 xjA1 = ld8(xbu + (size_t)jA * 64 + 32 + rg * 8);
  bf16x8 eA0  = ld8(eau + (size_t)(e0 + m) * 64 + rg * 8);
  bf16x8 eA1  = ld8(eau + (size_t)(e0 + m) * 64 + 32 + rg * 8);
  bf16x8 xiB0 = ld8(xbu + (size_t)iB * 64 + rg * 8);
  bf16x8 xiB1 = ld8(xbu + (size_t)iB * 64 + 32 + rg * 8);
  bf16x8 xjB0 = ld8(xbu + (size_t)jB * 64 + rg * 8);
  bf16x8 xjB1 = ld8(xbu + (size_t)jB * 64 + 32 + rg * 8);
  bf16x8 eB0  = ld8(eau + (size_t)(e0 + 16 + m) * 64 + rg * 8);
  bf16x8 eB1  = ld8(eau + (size_t)(e0 + 16 + m) * 64 + 32 + rg * 8);

  f32x4 pA0 = {0.f,0.f,0.f,0.f}, pA1 = pA0, pA2 = pA0, pA3 = pA0;
  f32x4 pB0 = pA0, pB1 = pA0, pB2 = pA0, pB3 = pA0;

#pragma unroll
  for (int t = 0; t < 16; ++t) {
    const unsigned short* wp = wtl + (t * 16 + m) * WTP + rg * 8;
    bf16x8 bx0 = ld8(wp);
    bf16x8 bx1 = ld8(wp + 32);
    bf16x8 be0 = ld8(wp + 64);
    bf16x8 be1 = ld8(wp + 96);
    f32x4 ciA = {0.f,0.f,0.f,0.f};
    ciA = MFMA(xiA0, bx0, ciA, 0, 0, 0);
    ciA = MFMA(xiA1, bx1, ciA, 0, 0, 0);
    ciA = MFMA(eA0,  be0, ciA, 0, 0, 0);
    ciA = MFMA(eA1,  be1, ciA, 0, 0, 0);
    f32x4 cjA = {0.f,0.f,0.f,0.f};
    cjA = MFMA(xjA0, bx0, cjA, 0, 0, 0);
    cjA = MFMA(xjA1, bx1, cjA, 0, 0, 0);
    cjA = MFMA(eA0,  be0, cjA, 0, 0, 0);
    cjA = MFMA(eA1,  be1, cjA, 0, 0, 0);
    f32x4 ciB = {0.f,0.f,0.f,0.f};
    ciB = MFMA(xiB0, bx0, ciB, 0, 0, 0);
    ciB = MFMA(xiB1, bx1, ciB, 0, 0, 0);
    ciB = MFMA(eB0,  be0, ciB, 0, 0, 0);
    ciB = MFMA(eB1,  be1, ciB, 0, 0, 0);
    f32x4 cjB = {0.f,0.f,0.f,0.f};
    cjB = MFMA(xjB0, bx0, cjB, 0, 0, 0);
    cjB = MFMA(xjB1, bx1, cjB, 0, 0, 0);
    cjB = MFMA(eB0,  be0, cjB, 0, 0, 0);
    cjB = MFMA(eB1,  be1, cjB, 0, 0, 0);
    const int h = t >> 2;
    const float ai = attl[h * 128 + (t & 3) * 16 + m];
    const float aj = attl[h * 128 + 64 + (t & 3) * 16 + m];
    pA0[h] = fmaf(softplusf(ciA[0]), ai, fmaf(softplusf(cjA[0]), aj, pA0[h]));
    pA1[h] = fmaf(softplusf(ciA[1]), ai, fmaf(softplusf(cjA[1]), aj, pA1[h]));
    pA2[h] = fmaf(softplusf(ciA[2]), ai, fmaf(softplusf(cjA[2]), aj, pA2[h]));
    pA3[h] = fmaf(softplusf(ciA[3]), ai, fmaf(softplusf(cjA[3]), aj, pA3[h]));
    pB0[h] = fmaf(softplusf(ciB[0]), ai, fmaf(softplusf(cjB[0]), aj, pB0[h]));
    pB1[h] = fmaf(softplusf(ciB[1]), ai, fmaf(softplusf(cjB[1]), aj, pB1[h]));
    pB2[h] = fmaf(softplusf(ciB[2]), ai, fmaf(softplusf(cjB[2]), aj, pB2[h]));
    pB3[h] = fmaf(softplusf(ciB[3]), ai, fmaf(softplusf(cjB[3]), aj, pB3[h]));
  }

  float bs = 0.f, ss = 0.f;
#pragma unroll
  for (int h = 0; h < 4; ++h) {
    pA0[h] += __shfl_xor(pA0[h], 1); pA0[h] += __shfl_xor(pA0[h], 2);
    pA0[h] += __shfl_xor(pA0[h], 4); pA0[h] += __shfl_xor(pA0[h], 8);
    pA1[h] += __shfl_xor(pA1[h], 1); pA1[h] += __shfl_xor(pA1[h], 2);
    pA1[h] += __shfl_xor(pA1[h], 4); pA1[h] += __shfl_xor(pA1[h], 8);
    pA2[h] += __shfl_xor(pA2[h], 1); pA2[h] += __shfl_xor(pA2[h], 2);
    pA2[h] += __shfl_xor(pA2[h], 4); pA2[h] += __shfl_xor(pA2[h], 8);
    pA3[h] += __shfl_xor(pA3[h], 1); pA3[h] += __shfl_xor(pA3[h], 2);
    pA3[h] += __shfl_xor(pA3[h], 4); pA3[h] += __shfl_xor(pA3[h], 8);
    pB0[h] += __shfl_xor(pB0[h], 1); pB0[h] += __shfl_xor(pB0[h], 2);
    pB0[h] += __shfl_xor(pB0[h], 4); pB0[h] += __shfl_xor(pB0[h], 8);
    pB1[h] += __shfl_xor(pB1[h], 1); pB1[h] += __shfl_xor(pB1[h], 2);
    pB1[h] += __shfl_xor(pB1[h], 4); pB1[h] += __shfl_xor(pB1[h], 8);
    pB2[h] += __shfl_xor(pB2[h], 1); pB2[h] += __shfl_xor(pB2[h], 2);
    pB2[h] += __shfl_xor(pB2[h], 4); pB2[h] += __shfl_xor(pB2[h], 8);
    pB3[h] += __shfl_xor(pB3[h], 1); pB3[h] += __shfl_xor(pB3[h], 2);
    pB3[h] += __shfl_xor(pB3[h], 4); pB3[h] += __shfl_xor(pB3[h], 8);
  }
  if (m < 4) {
    float vA0 = (m == 0) ? pA0[0] : (m == 1) ? pA0[1] : (m == 2) ? pA0[2] : pA0[3];
    float vA1 = (m == 0) ? pA1[0] : (m == 1) ? pA1[1] : (m == 2) ? pA1[2] : pA1[3];
    float vA2 = (m == 0) ? pA2[0] : (m == 1) ? pA2[1] : (m == 2) ? pA2[2] : pA2[3];
    float vA3 = (m == 0) ? pA3[0] : (m == 1) ? pA3[1] : (m == 2) ? pA3[2] : pA3[3];
    float vB0 = (m == 0) ? pB0[0] : (m == 1) ? pB0[1] : (m == 2) ? pB0[2] : pB0[3];
    float vB1 = (m == 0) ? pB1[0] : (m == 1) ? pB1[1] : (m == 2) ? pB1[2] : pB1[3];
    float vB2 = (m == 0) ? pB2[0] : (m == 1) ? pB2[1] : (m == 2) ? pB2[2] : pB2[3];
    float vB3 = (m == 0) ? pB3[0] : (m == 1) ? pB3[1] : (m == 2) ? pB3[2] : pB3[3];
    vA0 = softplusf(vA0); vA1 = softplusf(vA1); vA2 = softplusf(vA2); vA3 = softplusf(vA3);
    vB0 = softplusf(vB0); vB1 = softplusf(vB1); vB2 = softplusf(vB2); vB3 = softplusf(vB3);
    if (!oob) {
      alpha[(size_t)(e0 + rg * 4 + 0) * 4 + m] = vA0;
      alpha[(size_t)(e0 + rg * 4 + 1) * 4 + m] = vA1;
      alpha[(size_t)(e0 + rg * 4 + 2) * 4 + m] = vA2;
      alpha[(size_t)(e0 + rg * 4 + 3) * 4 + m] = vA3;
      alpha[(size_t)(e0 + 16 + rg * 4 + 0) * 4 + m] = vB0;
      alpha[(size_t)(e0 + 16 + rg * 4 + 1) * 4 + m] = vB1;
      alpha[(size_t)(e0 + 16 + rg * 4 + 2) * 4 + m] = vB2;
      alpha[(size_t)(e0 + 16 + rg * 4 + 3) * 4 + m] = vB3;
      bs = vA0 + vA1 + vA2 + vA3 + vB0 + vB1 + vB2 + vB3;
      ss = vA0*vA0 + vA1*vA1 + vA2*vA2 + vA3*vA3 + vB0*vB0 + vB1*vB1 + vB2*vB2 + vB3*vB3;
    }
  }
  bs += __shfl_xor(bs, 16); bs += __shfl_xor(bs, 32);
  ss += __shfl_xor(ss, 16); ss += __shfl_xor(ss, 32);
  if (lane < 4) { red[wave * 8 + lane] = bs; red[wave * 8 + 4 + lane] = ss; }
  __syncthreads();
  if (threadIdx.x < 8) {
    float s = 0.f;
#pragma unroll
    for (int w2 = 0; w2 < 8; ++w2) s += red[w2 * 8 + threadIdx.x];
    atomicAdd(&bnst[threadIdx.x], s);
  }
}

// ---------- pass 2: BN finalize ----------
__global__ void k_bn_fin(float* __restrict__ bnst, const float* __restrict__ gamma)
{
  int q = threadIdx.x;
  if (q < 4) {
    float mu = bnst[q] * (1.0f / NE);
    float var = bnst[4 + q] * (1.0f / NE) - mu * mu;
    bnst[8 + q] = mu;
    bnst[12 + q] = rsqrtf(var + 1e-5f) * gamma[q];
  }
}

// ---------- pass 3: alpha = exp(softplus(BN(alpha))); segment sum ----------
__global__ __launch_bounds__(256)
void k_bn_expsum(float* __restrict__ alpha, const int* __restrict__ idx,
                 const float* __restrict__ bnst, const float* __restrict__ beta,
                 float* __restrict__ segsum)
{
  int e = blockIdx.x * 256 + threadIdx.x;
  if (e >= NE) return;
  float4 a = *reinterpret_cast<const float4*>(&alpha[(size_t)e * 4]);
  int n = idx[e];
  a.x = expsp((a.x - bnst[8])  * bnst[12] + beta[0]);
  a.y = expsp((a.y - bnst[9])  * bnst[13] + beta[1]);
  a.z = expsp((a.z - bnst[10]) * bnst[14] + beta[2]);
  a.w = expsp((a.w - bnst[11]) * bnst[15] + beta[3]);
  *reinterpret_cast<float4*>(&alpha[(size_t)e * 4]) = a;
  atomicAdd(&segsum[n * 4 + 0], a.x);
  atomicAdd(&segsum[n * 4 + 1], a.y);
  atomicAdd(&segsum[n * 4 + 2], a.z);
  atomicAdd(&segsum[n * 4 + 3], a.w);
}

// ---------- pass 4: out_j recompute (MFMA, wt in LDS) + weighted aggregation ----------
// atomics go to replica (wave & 3) of aggr to cut per-line atomic contention 4x
__global__ __launch_bounds__(512, 2)
void k_edge_aggr(const __hip_bfloat16* __restrict__ xb,
                 const __hip_bfloat16* __restrict__ eab,
                 const __hip_bfloat16* __restrict__ wt,
                 const int* __restrict__ idx, const float* __restrict__ alpha,
                 const float* __restrict__ segsum, float* __restrict__ aggr)
{
  __shared__ __align__(16) unsigned short wtl[256 * WTP];
  const unsigned short* wtu = reinterpret_cast<const unsigned short*>(wt);
  stage_wt(wtl, wtu, threadIdx.x);
  __syncthreads();

  const int wave = threadIdx.x >> 6, lane = threadIdx.x & 63;
  const int m = lane & 15, rg = lane >> 4;
  const unsigned short* xbu = reinterpret_cast<const unsigned short*>(xb);
  const unsigned short* eau = reinterpret_cast<const unsigned short*>(eab);
  const int e0r = blockIdx.x * 256 + wave * 32;
  const bool oob = (e0r >= NE);
  const int e0 = oob ? 0 : e0r;
  float* aggrR = aggr + (size_t)(wave & 3) * (NN * 64);

  const int jA = idx[NE + e0 + m], jB = idx[NE + e0 + 16 + m];
  bf16x8 xjA0 = ld8(xbu + (size_t)jA * 64 + rg * 8);
  bf16x8 xjA1 = ld8(xbu + (size_t)jA * 64 + 32 + rg * 8);
  bf16x8 eA0  = ld8(eau + (size_t)(e0 + m) * 64 + rg * 8);
  bf16x8 eA1  = ld8(eau + (size_t)(e0 + m) * 64 + 32 + rg * 8);
  bf16x8 xjB0 = ld8(xbu + (size_t)jB * 64 + rg * 8);
  bf16x8 xjB1 = ld8(xbu + (size_t)jB * 64 + 32 + rg * 8);
  bf16x8 eB0  = ld8(eau + (size_t)(e0 + 16 + m) * 64 + rg * 8);
  bf16x8 eB1  = ld8(eau + (size_t)(e0 + 16 + m) * 64 + 32 + rg * 8);

  const int iA0 = idx[e0 + rg * 4 + 0];
  const int iA1 = idx[e0 + rg * 4 + 1];
  const int iA2 = idx[e0 + rg * 4 + 2];
  const int iA3 = idx[e0 + rg * 4 + 3];
  const int iB0 = idx[e0 + 16 + rg * 4 + 0];
  const int iB1 = idx[e0 + 16 + rg * 4 + 1];
  const int iB2 = idx[e0 + 16 + rg * 4 + 2];
  const int iB3 = idx[e0 + 16 + rg * 4 + 3];

  f32x4 wA0, wA1, wA2, wA3, wB0, wB1, wB2, wB3;
  {
    f32x4 ev0 = *reinterpret_cast<const f32x4*>(alpha + (size_t)(e0 + rg * 4 + 0) * 4);
    f32x4 ev1 = *reinterpret_cast<const f32x4*>(alpha + (size_t)(e0 + rg * 4 + 1) * 4);
    f32x4 ev2 = *reinterpret_cast<const f32x4*>(alpha + (size_t)(e0 + rg * 4 + 2) * 4);
    f32x4 ev3 = *reinterpret_cast<const f32x4*>(alpha + (size_t)(e0 + rg * 4 + 3) * 4);
    f32x4 fv0 = *reinterpret_cast<const f32x4*>(alpha + (size_t)(e0 + 16 + rg * 4 + 0) * 4);
    f32x4 fv1 = *reinterpret_cast<const f32x4*>(alpha + (size_t)(e0 + 16 + rg * 4 + 1) * 4);
    f32x4 fv2 = *reinterpret_cast<const f32x4*>(alpha + (size_t)(e0 + 16 + rg * 4 + 2) * 4);
    f32x4 fv3 = *reinterpret_cast<const f32x4*>(alpha + (size_t)(e0 + 16 + rg * 4 + 3) * 4);
    f32x4 sA0 = *reinterpret_cast<const f32x4*>(segsum + (size_t)iA0 * 4);
    f32x4 sA1 = *reinterpret_cast<const f32x4*>(segsum + (size_t)iA1 * 4);
    f32x4 sA2 = *reinterpret_cast<const f32x4*>(segsum + (size_t)iA2 * 4);
    f32x4 sA3 = *reinterpret_cast<const f32x4*>(segsum + (size_t)iA3 * 4);
    f32x4 sB0 = *reinterpret_cast<const f32x4*>(segsum + (size_t)iB0 * 4);
    f32x4 sB1 = *reinterpret_cast<const f32x4*>(segsum + (size_t)iB1 * 4);
    f32x4 sB2 = *reinterpret_cast<const f32x4*>(segsum + (size_t)iB2 * 4);
    f32x4 sB3 = *reinterpret_cast<const f32x4*>(segsum + (size_t)iB3 * 4);
#pragma unroll
    for (int h = 0; h < 4; ++h) {
      wA0[h] = 0.25f * ev0[h] / (sA0[h] + 1e-16f);
      wA1[h] = 0.25f * ev1[h] / (sA1[h] + 1e-16f);
      wA2[h] = 0.25f * ev2[h] / (sA2[h] + 1e-16f);
      wA3[h] = 0.25f * ev3[h] / (sA3[h] + 1e-16f);
      wB0[h] = 0.25f * fv0[h] / (sB0[h] + 1e-16f);
      wB1[h] = 0.25f * fv1[h] / (sB1[h] + 1e-16f);
      wB2[h] = 0.25f * fv2[h] / (sB2[h] + 1e-16f);
      wB3[h] = 0.25f * fv3[h] / (sB3[h] + 1e-16f);
    }
  }

  f32x4 cA0 = {0.f,0.f,0.f,0.f}, cA1 = cA0, cA2 = cA0, cA3 = cA0;
  f32x4 cB0 = cA0, cB1 = cA0, cB2 = cA0, cB3 = cA0;

#pragma unroll
  for (int t = 0; t < 16; ++t) {
    const unsigned short* wp = wtl + (t * 16 + m) * WTP + rg * 8;
    bf16x8 bx0 = ld8(wp);
    bf16x8 bx1 = ld8(wp + 32);
    bf16x8 be0 = ld8(wp + 64);
    bf16x8 be1 = ld8(wp + 96);
    f32x4 cjA = {0.f,0.f,0.f,0.f};
    cjA = MFMA(xjA0, bx0, cjA, 0, 0, 0);
    cjA = MFMA(xjA1, bx1, cjA, 0, 0, 0);
    cjA = MFMA(eA0,  be0, cjA, 0, 0, 0);
    cjA = MFMA(eA1,  be1, cjA, 0, 0, 0);
    f32x4 cjB = {0.f,0.f,0.f,0.f};
    cjB = MFMA(xjB0, bx0, cjB, 0, 0, 0);
    cjB = MFMA(xjB1, bx1, cjB, 0, 0, 0);
    cjB = MFMA(eB0,  be0, cjB, 0, 0, 0);
    cjB = MFMA(eB1,  be1, cjB, 0, 0, 0);
    const int h = t >> 2, tq = t & 3;
    cA0[tq] = fmaf(softplusf(cjA[0]), wA0[h], cA0[tq]);
    cA1[tq] = fmaf(softplusf(cjA[1]), wA1[h], cA1[tq]);
    cA2[tq] = fmaf(softplusf(cjA[2]), wA2[h], cA2[tq]);
    cA3[tq] = fmaf(softplusf(cjA[3]), wA3[h], cA3[tq]);
    cB0[tq] = fmaf(softplusf(cjB[0]), wB0[h], cB0[tq]);
    cB1[tq] = fmaf(softplusf(cjB[1]), wB1[h], cB1[tq]);
    cB2[tq] = fmaf(softplusf(cjB[2]), wB2[h], cB2[tq]);
    cB3[tq] = fmaf(softplusf(cjB[3]), wB3[h], cB3[tq]);
  }

  if (!oob) {
#pragma unroll
    for (int tq = 0; tq < 4; ++tq) {
      atomicAdd(&aggrR[(size_t)iA0 * 64 + tq * 16 + m], cA0[tq]);
      atomicAdd(&aggrR[(size_t)iA1 * 64 + tq * 16 + m], cA1[tq]);
      atomicAdd(&aggrR[(size_t)iA2 * 64 + tq * 16 + m], cA2[tq]);
      atomicAdd(&aggrR[(size_t)iA3 * 64 + tq * 16 + m], cA3[tq]);
      atomicAdd(&aggrR[(size_t)iB0 * 64 + tq * 16 + m], cB0[tq]);
      atomicAdd(&aggrR[(size_t)iB1 * 64 + tq * 16 + m], cB1[tq]);
      atomicAdd(&aggrR[(size_t)iB2 * 64 + tq * 16 + m], cB2[tq]);
      atomicAdd(&aggrR[(size_t)iB3 * 64 + tq * 16 + m], cB3[tq]);
    }
  }
}

// ---------- pass 5: out = sum of 4 aggr replicas + bias ----------
__global__ __launch_bounds__(256)
void k_final(const float* __restrict__ aggr, const float* __restrict__ bias,
             float* __restrict__ out)
{
  int t = blockIdx.x * 256 + threadIdx.x;
  float s = aggr[t] + aggr[t + NN * 64] + aggr[t + 2 * NN * 64] + aggr[t + 3 * NN * 64];
  out[t] = s + bias[t & 63];
}

extern "C" void kernel_launch(void* const* d_in, const int* in_sizes, int n_in,
                              void* d_out, int out_size, void* d_ws, size_t ws_size,
                              hipStream_t stream)
{
  const float* x    = (const float*)d_in[0];
  const float* ea   = (const float*)d_in[1];
  const float* W    = (const float*)d_in[2];
  const float* att  = (const float*)d_in[3];
  const float* bias = (const float*)d_in[4];
  const float* gam  = (const float*)d_in[5];
  const float* bet  = (const float*)d_in[6];
  const unsigned* idx_raw = (const unsigned*)d_in[7];
  float* out = (float*)d_out;

  char* ws = (char*)d_ws;
  float*    alpha  = (float*)(ws + OFF_ALPHA);
  float*    segsum = (float*)(ws + OFF_SEGSUM);
  float*    bnst   = (float*)(ws + OFF_BN);
  unsigned* flag   = (unsigned*)(ws + OFF_BN + 64);
  float*    aggr   = (float*)(ws + OFF_AGGR);
  int*      idx    = (int*)(ws + OFF_IDX32);
  __hip_bfloat16* wt  = (__hip_bfloat16*)(ws + OFF_WT);
  __hip_bfloat16* xb  = (__hip_bfloat16*)(ws + OFF_XB);
  __hip_bfloat16* eab = (__hip_bfloat16*)(ws + OFF_EAB);

  hipMemsetAsync(ws + OFF_SEGSUM, 0, Z_SZ, stream);
  k_wprep<<<128, 256, 0, stream>>>(W, wt);
  k_idx_detect<<<(NE + 255) / 256, 256, 0, stream>>>(idx_raw, flag);
  k_idx_cvt<<<(2 * NE) / 256, 256, 0, stream>>>(idx_raw, flag, idx);
  k_cvt_bf16<<<(NN * 64 / 4) / 256, 256, 0, stream>>>(x, (unsigned*)xb);
  k_cvt_bf16<<<(NE * 64 / 4) / 256, 256, 0, stream>>>(ea, (unsigned*)eab);

  const int NB = (NE + 255) / 256;   // 1563, last block tail-guarded per wave
  k_edge_alpha<<<NB, 512, 0, stream>>>(xb, eab, wt, att, idx, alpha, bnst);
  k_bn_fin<<<1, 64, 0, stream>>>(bnst, gam);
  k_bn_expsum<<<(NE + 255) / 256, 256, 0, stream>>>(alpha, idx, bnst, bet, segsum);
  k_edge_aggr<<<NB, 512, 0, stream>>>(xb, eab, wt, idx, alpha, segsum, aggr);
  k_final<<<(NN * 64) / 256, 256, 0, stream>>>(aggr, bias, out);
}

// Round 13
// 446.321 us; speedup vs baseline: 1.0765x; 1.0765x over previous
//
#include <hip/hip_runtime.h>
#include <hip/hip_bf16.h>

#define NN 50000
#define NE 400000
#define WTP 136   // padded LDS row (elems): 272B = 17*16B -> 2-way banks, 16B aligned

// ---- workspace layout (bytes) ----
static const size_t OFF_ALPHA  = 0;                       // [NE,4]  f32 =  6,400,000
static const size_t OFF_SEGSUM = 6400000;                 // [NN,4]  f32 =    800,000
static const size_t OFF_BN     = 7200000;                 // 16 f32 + flag =      256
static const size_t OFF_AGGR   = 7200256;                 // [NN,64] f32 = 12,800,000
static const size_t OFF_IDX32  = 20000256;                // [2,NE]  i32 =  3,200,000
static const size_t OFF_WT     = 23200256;                // [256,128] bf16 =  65,536
static const size_t OFF_XB     = 23265792;                // [NN,64] bf16 =  6,400,000
static const size_t OFF_EAB    = 29665792;                // [NE,64] bf16 = 51,200,000
static const size_t Z_SZ       = OFF_IDX32 - OFF_SEGSUM;  // segsum+bn+aggr zeroed

typedef __attribute__((ext_vector_type(8))) __bf16 bf16x8;
typedef __attribute__((ext_vector_type(4))) float  f32x4;
typedef __attribute__((ext_vector_type(4))) int    i32x4;
typedef __attribute__((ext_vector_type(2))) unsigned u32x2;

#define L2E 1.44269504f
#define LN2 0.69314718f

__device__ __forceinline__ float fexp2(float x) {
  float r; asm("v_exp_f32 %0, %1" : "=v"(r) : "v"(x)); return r;
}
__device__ __forceinline__ float flog2(float x) {
  float r; asm("v_log_f32 %0, %1" : "=v"(r) : "v"(x)); return r;
}
__device__ __forceinline__ float softplusf(float x) {
  return fmaxf(x, 0.0f) + LN2 * flog2(1.0f + fexp2(-L2E * fabsf(x)));
}
__device__ __forceinline__ float expsp(float y) {
  return fexp2(L2E * fmaxf(y, 0.0f)) * (1.0f + fexp2(-L2E * fabsf(y)));
}
__device__ __forceinline__ unsigned bfbits(float f) {
  return (unsigned)__builtin_bit_cast(unsigned short, __float2bfloat16(f));
}
__device__ __forceinline__ unsigned pkbf(float a, float b) {
  return bfbits(a) | (bfbits(b) << 16);
}
__device__ __forceinline__ bf16x8 ld8(const unsigned short* p) {
  return __builtin_bit_cast(bf16x8, *reinterpret_cast<const i32x4*>(p));
}
// non-temporal (nt) load: read-once streams must not evict atomic lines from L2
__device__ __forceinline__ bf16x8 ld8nt(const unsigned short* p) {
  i32x4 v = __builtin_nontemporal_load(reinterpret_cast<const i32x4*>(p));
  return __builtin_bit_cast(bf16x8, v);
}
__device__ __forceinline__ f32x4 ld4fnt(const float* p) {
  return __builtin_nontemporal_load(reinterpret_cast<const f32x4*>(p));
}
#define MFMA __builtin_amdgcn_mfma_f32_16x16x32_bf16

// ---------- idx dtype detect + convert ----------
__global__ __launch_bounds__(256)
void k_idx_detect(const unsigned* __restrict__ src, unsigned* __restrict__ flag)
{
  int t = blockIdx.x * 256 + threadIdx.x;
  unsigned v = (t < NE) ? src[2 * t + 1] : 0u;
  if (__any(v != 0)) { if ((threadIdx.x & 63) == 0) atomicOr(flag, 1u); }
}
__global__ __launch_bounds__(256)
void k_idx_cvt(const unsigned* __restrict__ src, const unsigned* __restrict__ flag,
               int* __restrict__ dst)
{
  int e = blockIdx.x * 256 + threadIdx.x;
  unsigned f = *flag;
  dst[e] = (int)(f ? src[e] : src[2 * e]);
}

// ---------- Wt[c][k] = bf16(W[k][c]), [256 cols][128 k] = 64KB ----------
__global__ __launch_bounds__(256)
void k_wprep(const float* __restrict__ W, __hip_bfloat16* __restrict__ wt)
{
  int t = blockIdx.x * 256 + threadIdx.x;
  int k = t >> 8, c = t & 255;
  wt[c * 128 + k] = __float2bfloat16(W[t]);
}

// ---------- f32 -> bf16 bulk convert ----------
__global__ __launch_bounds__(256)
void k_cvt_bf16(const float* __restrict__ src, unsigned* __restrict__ dst)
{
  int t = blockIdx.x * 256 + threadIdx.x;
  f32x4 v = *reinterpret_cast<const f32x4*>(src + (size_t)t * 4);
  u32x2 p = { pkbf(v[0], v[1]), pkbf(v[2], v[3]) };
  *reinterpret_cast<u32x2*>(dst + (size_t)t * 2) = p;
}

// ---------- stage wt into padded LDS (alpha kernel) ----------
__device__ __forceinline__ void stage_wt(unsigned short* wtl,
                                         const unsigned short* wtu, int tid)
{
  for (int it = tid; it < 4096; it += 512) {           // 4096 * 16B = 64KB
    int c = it >> 4, k8 = (it & 15) << 3;
    *reinterpret_cast<i32x4*>(&wtl[c * WTP + k8]) =
        *reinterpret_cast<const i32x4*>(wtu + c * 128 + k8);
  }
}

// ---------- pass 1: [x,ea]@W via MFMA; 32 edges/wave, wt in LDS ----------
__global__ __launch_bounds__(512, 2)
void k_edge_alpha(const __hip_bfloat16* __restrict__ xb,
                  const __hip_bfloat16* __restrict__ eab,
                  const __hip_bfloat16* __restrict__ wt,
                  const float* __restrict__ att, const int* __restrict__ idx,
                  float* __restrict__ alpha, float* __restrict__ bnst)
{
  __shared__ __align__(16) unsigned short wtl[256 * WTP];
  __shared__ float attl[512];
  __shared__ float red[64];
  const unsigned short* wtu = reinterpret_cast<const unsigned short*>(wt);
  stage_wt(wtl, wtu, threadIdx.x);
  if (threadIdx.x < 512) attl[threadIdx.x] = att[threadIdx.x];
  __syncthreads();

  const int wave = threadIdx.x >> 6, lane = threadIdx.x & 63;
  const int m = lane & 15, rg = lane >> 4;
  const unsigned short* xbu = reinterpret_cast<const unsigned short*>(xb);
  const unsigned short* eau = reinterpret_cast<const unsigned short*>(eab);
  const int e0r = blockIdx.x * 256 + wave * 32;
  const bool oob = (e0r >= NE);          // wave-uniform (NE % 32 == 0)
  const int e0 = oob ? 0 : e0r;

  const int iA = idx[e0 + m],      jA = idx[NE + e0 + m];
  const int iB = idx[e0 + 16 + m], jB = idx[NE + e0 + 16 + m];
  bf16x8 xiA0 = ld8(xbu + (size_t)iA * 64 + rg * 8);
  bf16x8 xiA1 = ld8(xbu + (size_t)iA * 64 + 32 + rg * 8);
  bf16x8 xjA0 = ld8(xbu + (size_t)jA * 64 + rg * 8);
  bf16x8 xjA1 = ld8(xbu + (size_t)jA * 64 + 32 + rg * 8);
  bf16x8 eA0  = ld8nt(eau + (size_t)(e0 + m) * 64 + rg * 8);
  bf16x8 eA1  = ld8nt(eau + (size_t)(e0 + m) * 64 + 32 + rg * 8);
  bf16x8 xiB0 = ld8(xbu + (size_t)iB * 64 + rg * 8);
  bf16x8 xiB1 = ld8(xbu + (size_t)iB * 64 + 32 + rg * 8);
  bf16x8 xjB0 = ld8(xbu + (size_t)jB * 64 + rg * 8);
  bf16x8 xjB1 = ld8(xbu + (size_t)jB * 64 + 32 + rg * 8);
  bf16x8 eB0  = ld8nt(eau + (size_t)(e0 + 16 + m) * 64 + rg * 8);
  bf16x8 eB1  = ld8nt(eau + (size_t)(e0 + 16 + m) * 64 + 32 + rg * 8);

  f32x4 pA0 = {0.f,0.f,0.f,0.f}, pA1 = pA0, pA2 = pA0, pA3 = pA0;
  f32x4 pB0 = pA0, pB1 = pA0, pB2 = pA0, pB3 = pA0;

#pragma unroll
  for (int t = 0; t < 16; ++t) {
    const unsigned short* wp = wtl + (t * 16 + m) * WTP + rg * 8;
    bf16x8 bx0 = ld8(wp);
    bf16x8 bx1 = ld8(wp + 32);
    bf16x8 be0 = ld8(wp + 64);
    bf16x8 be1 = ld8(wp + 96);
    f32x4 ciA = {0.f,0.f,0.f,0.f};
    ciA = MFMA(xiA0, bx0, ciA, 0, 0, 0);
    ciA = MFMA(xiA1, bx1, ciA, 0, 0, 0);
    ciA = MFMA(eA0,  be0, ciA, 0, 0, 0);
    ciA = MFMA(eA1,  be1, ciA, 0, 0, 0);
    f32x4 cjA = {0.f,0.f,0.f,0.f};
    cjA = MFMA(xjA0, bx0, cjA, 0, 0, 0);
    cjA = MFMA(xjA1, bx1, cjA, 0, 0, 0);
    cjA = MFMA(eA0,  be0, cjA, 0, 0, 0);
    cjA = MFMA(eA1,  be1, cjA, 0, 0, 0);
    f32x4 ciB = {0.f,0.f,0.f,0.f};
    ciB = MFMA(xiB0, bx0, ciB, 0, 0, 0);
    ciB = MFMA(xiB1, bx1, ciB, 0, 0, 0);
    ciB = MFMA(eB0,  be0, ciB, 0, 0, 0);
    ciB = MFMA(eB1,  be1, ciB, 0, 0, 0);
    f32x4 cjB = {0.f,0.f,0.f,0.f};
    cjB = MFMA(xjB0, bx0, cjB, 0, 0, 0);
    cjB = MFMA(xjB1, bx1, cjB, 0, 0, 0);
    cjB = MFMA(eB0,  be0, cjB, 0, 0, 0);
    cjB = MFMA(eB1,  be1, cjB, 0, 0, 0);
    const int h = t >> 2;
    const float ai = attl[h * 128 + (t & 3) * 16 + m];
    const float aj = attl[h * 128 + 64 + (t & 3) * 16 + m];
    pA0[h] = fmaf(softplusf(ciA[0]), ai, fmaf(softplusf(cjA[0]), aj, pA0[h]));
    pA1[h] = fmaf(softplusf(ciA[1]), ai, fmaf(softplusf(cjA[1]), aj, pA1[h]));
    pA2[h] = fmaf(softplusf(ciA[2]), ai, fmaf(softplusf(cjA[2]), aj, pA2[h]));
    pA3[h] = fmaf(softplusf(ciA[3]), ai, fmaf(softplusf(cjA[3]), aj, pA3[h]));
    pB0[h] = fmaf(softplusf(ciB[0]), ai, fmaf(softplusf(cjB[0]), aj, pB0[h]));
    pB1[h] = fmaf(softplusf(ciB[1]), ai, fmaf(softplusf(cjB[1]), aj, pB1[h]));
    pB2[h] = fmaf(softplusf(ciB[2]), ai, fmaf(softplusf(cjB[2]), aj, pB2[h]));
    pB3[h] = fmaf(softplusf(ciB[3]), ai, fmaf(softplusf(cjB[3]), aj, pB3[h]));
  }

  float bs = 0.f, ss = 0.f;
#pragma unroll
  for (int h = 0; h < 4; ++h) {
    pA0[h] += __shfl_xor(pA0[h], 1); pA0[h] += __shfl_xor(pA0[h], 2);
    pA0[h] += __shfl_xor(pA0[h], 4); pA0[h] += __shfl_xor(pA0[h], 8);
    pA1[h] += __shfl_xor(pA1[h], 1); pA1[h] += __shfl_xor(pA1[h], 2);
    pA1[h] += __shfl_xor(pA1[h], 4); pA1[h] += __shfl_xor(pA1[h], 8);
    pA2[h] += __shfl_xor(pA2[h], 1); pA2[h] += __shfl_xor(pA2[h], 2);
    pA2[h] += __shfl_xor(pA2[h], 4); pA2[h] += __shfl_xor(pA2[h], 8);
    pA3[h] += __shfl_xor(pA3[h], 1); pA3[h] += __shfl_xor(pA3[h], 2);
    pA3[h] += __shfl_xor(pA3[h], 4); pA3[h] += __shfl_xor(pA3[h], 8);
    pB0[h] += __shfl_xor(pB0[h], 1); pB0[h] += __shfl_xor(pB0[h], 2);
    pB0[h] += __shfl_xor(pB0[h], 4); pB0[h] += __shfl_xor(pB0[h], 8);
    pB1[h] += __shfl_xor(pB1[h], 1); pB1[h] += __shfl_xor(pB1[h], 2);
    pB1[h] += __shfl_xor(pB1[h], 4); pB1[h] += __shfl_xor(pB1[h], 8);
    pB2[h] += __shfl_xor(pB2[h], 1); pB2[h] += __shfl_xor(pB2[h], 2);
    pB2[h] += __shfl_xor(pB2[h], 4); pB2[h] += __shfl_xor(pB2[h], 8);
    pB3[h] += __shfl_xor(pB3[h], 1); pB3[h] += __shfl_xor(pB3[h], 2);
    pB3[h] += __shfl_xor(pB3[h], 4); pB3[h] += __shfl_xor(pB3[h], 8);
  }
  if (m < 4) {
    float vA0 = (m == 0) ? pA0[0] : (m == 1) ? pA0[1] : (m == 2) ? pA0[2] : pA0[3];
    float vA1 = (m == 0) ? pA1[0] : (m == 1) ? pA1[1] : (m == 2) ? pA1[2] : pA1[3];
    float vA2 = (m == 0) ? pA2[0] : (m == 1) ? pA2[1] : (m == 2) ? pA2[2] : pA2[3];
    float vA3 = (m == 0) ? pA3[0] : (m == 1) ? pA3[1] : (m == 2) ? pA3[2] : pA3[3];
    float vB0 = (m == 0) ? pB0[0] : (m == 1) ? pB0[1] : (m == 2) ? pB0[2] : pB0[3];
    float vB1 = (m == 0) ? pB1[0] : (m == 1) ? pB1[1] : (m == 2) ? pB1[2] : pB1[3];
    float vB2 = (m == 0) ? pB2[0] : (m == 1) ? pB2[1] : (m == 2) ? pB2[2] : pB2[3];
    float vB3 = (m == 0) ? pB3[0] : (m == 1) ? pB3[1] : (m == 2) ? pB3[2] : pB3[3];
    vA0 = softplusf(vA0); vA1 = softplusf(vA1); vA2 = softplusf(vA2); vA3 = softplusf(vA3);
    vB0 = softplusf(vB0); vB1 = softplusf(vB1); vB2 = softplusf(vB2); vB3 = softplusf(vB3);
    if (!oob) {
      alpha[(size_t)(e0 + rg * 4 + 0) * 4 + m] = vA0;
      alpha[(size_t)(e0 + rg * 4 + 1) * 4 + m] = vA1;
      alpha[(size_t)(e0 + rg * 4 + 2) * 4 + m] = vA2;
      alpha[(size_t)(e0 + rg * 4 + 3) * 4 + m] = vA3;
      alpha[(size_t)(e0 + 16 + rg * 4 + 0) * 4 + m] = vB0;
      alpha[(size_t)(e0 + 16 + rg * 4 + 1) * 4 + m] = vB1;
      alpha[(size_t)(e0 + 16 + rg * 4 + 2) * 4 + m] = vB2;
      alpha[(size_t)(e0 + 16 + rg * 4 + 3) * 4 + m] = vB3;
      bs = vA0 + vA1 + vA2 + vA3 + vB0 + vB1 + vB2 + vB3;
      ss = vA0*vA0 + vA1*vA1 + vA2*vA2 + vA3*vA3 + vB0*vB0 + vB1*vB1 + vB2*vB2 + vB3*vB3;
    }
  }
  bs += __shfl_xor(bs, 16); bs += __shfl_xor(bs, 32);
  ss += __shfl_xor(ss, 16); ss += __shfl_xor(ss, 32);
  if (lane < 4) { red[wave * 8 + lane] = bs; red[wave * 8 + 4 + lane] = ss; }
  __syncthreads();
  if (threadIdx.x < 8) {
    float s = 0.f;
#pragma unroll
    for (int w2 = 0; w2 < 8; ++w2) s += red[w2 * 8 + threadIdx.x];
    atomicAdd(&bnst[threadIdx.x], s);
  }
}

// ---------- pass 2: BN finalize ----------
__global__ void k_bn_fin(float* __restrict__ bnst, const float* __restrict__ gamma)
{
  int q = threadIdx.x;
  if (q < 4) {
    float mu = bnst[q] * (1.0f / NE);
    float var = bnst[4 + q] * (1.0f / NE) - mu * mu;
    bnst[8 + q] = mu;
    bnst[12 + q] = rsqrtf(var + 1e-5f) * gamma[q];
  }
}

// ---------- pass 3: alpha = exp(softplus(BN(alpha))); segment sum ----------
__global__ __launch_bounds__(256)
void k_bn_expsum(float* __restrict__ alpha, const int* __restrict__ idx,
                 const float* __restrict__ bnst, const float* __restrict__ beta,
                 float* __restrict__ segsum)
{
  int e = blockIdx.x * 256 + threadIdx.x;
  if (e >= NE) return;
  float4 a = *reinterpret_cast<const float4*>(&alpha[(size_t)e * 4]);
  int n = idx[e];
  a.x = expsp((a.x - bnst[8])  * bnst[12] + beta[0]);
  a.y = expsp((a.y - bnst[9])  * bnst[13] + beta[1]);
  a.z = expsp((a.z - bnst[10]) * bnst[14] + beta[2]);
  a.w = expsp((a.w - bnst[11]) * bnst[15] + beta[3]);
  *reinterpret_cast<float4*>(&alpha[(size_t)e * 4]) = a;
  atomicAdd(&segsum[n * 4 + 0], a.x);
  atomicAdd(&segsum[n * 4 + 1], a.y);
  atomicAdd(&segsum[n * 4 + 2], a.z);
  atomicAdd(&segsum[n * 4 + 3], a.w);
}

// ---------- pass 4: out_j recompute (MFMA, wt from L2) + weighted aggregation ----------
// round-9 structure (256 threads, no LDS) + nt loads on read-once streams
__global__ __launch_bounds__(256, 3)
void k_edge_aggr(const __hip_bfloat16* __restrict__ xb,
                 const __hip_bfloat16* __restrict__ eab,
                 const __hip_bfloat16* __restrict__ wt,
                 const int* __restrict__ idx, const float* __restrict__ alpha,
                 const float* __restrict__ segsum, float* __restrict__ aggr)
{
  const int wave = threadIdx.x >> 6, lane = threadIdx.x & 63;
  const int m = lane & 15, rg = lane >> 4;
  const unsigned short* xbu = reinterpret_cast<const unsigned short*>(xb);
  const unsigned short* eau = reinterpret_cast<const unsigned short*>(eab);
  const unsigned short* wtu = reinterpret_cast<const unsigned short*>(wt);
  const int e0 = blockIdx.x * 128 + wave * 32;   // edges e0..e0+31

  const int jA = idx[NE + e0 + m], jB = idx[NE + e0 + 16 + m];
  bf16x8 xjA0 = ld8(xbu + (size_t)jA * 64 + rg * 8);
  bf16x8 xjA1 = ld8(xbu + (size_t)jA * 64 + 32 + rg * 8);
  bf16x8 eA0  = ld8nt(eau + (size_t)(e0 + m) * 64 + rg * 8);
  bf16x8 eA1  = ld8nt(eau + (size_t)(e0 + m) * 64 + 32 + rg * 8);
  bf16x8 xjB0 = ld8(xbu + (size_t)jB * 64 + rg * 8);
  bf16x8 xjB1 = ld8(xbu + (size_t)jB * 64 + 32 + rg * 8);
  bf16x8 eB0  = ld8nt(eau + (size_t)(e0 + 16 + m) * 64 + rg * 8);
  bf16x8 eB1  = ld8nt(eau + (size_t)(e0 + 16 + m) * 64 + 32 + rg * 8);

  const int iA0 = idx[e0 + rg * 4 + 0];
  const int iA1 = idx[e0 + rg * 4 + 1];
  const int iA2 = idx[e0 + rg * 4 + 2];
  const int iA3 = idx[e0 + rg * 4 + 3];
  const int iB0 = idx[e0 + 16 + rg * 4 + 0];
  const int iB1 = idx[e0 + 16 + rg * 4 + 1];
  const int iB2 = idx[e0 + 16 + rg * 4 + 2];
  const int iB3 = idx[e0 + 16 + rg * 4 + 3];

  f32x4 wA0, wA1, wA2, wA3, wB0, wB1, wB2, wB3;
  {
    f32x4 ev0 = ld4fnt(alpha + (size_t)(e0 + rg * 4 + 0) * 4);
    f32x4 ev1 = ld4fnt(alpha + (size_t)(e0 + rg * 4 + 1) * 4);
    f32x4 ev2 = ld4fnt(alpha + (size_t)(e0 + rg * 4 + 2) * 4);
    f32x4 ev3 = ld4fnt(alpha + (size_t)(e0 + rg * 4 + 3) * 4);
    f32x4 fv0 = ld4fnt(alpha + (size_t)(e0 + 16 + rg * 4 + 0) * 4);
    f32x4 fv1 = ld4fnt(alpha + (size_t)(e0 + 16 + rg * 4 + 1) * 4);
    f32x4 fv2 = ld4fnt(alpha + (size_t)(e0 + 16 + rg * 4 + 2) * 4);
    f32x4 fv3 = ld4fnt(alpha + (size_t)(e0 + 16 + rg * 4 + 3) * 4);
    f32x4 sA0 = *reinterpret_cast<const f32x4*>(segsum + (size_t)iA0 * 4);
    f32x4 sA1 = *reinterpret_cast<const f32x4*>(segsum + (size_t)iA1 * 4);
    f32x4 sA2 = *reinterpret_cast<const f32x4*>(segsum + (size_t)iA2 * 4);
    f32x4 sA3 = *reinterpret_cast<const f32x4*>(segsum + (size_t)iA3 * 4);
    f32x4 sB0 = *reinterpret_cast<const f32x4*>(segsum + (size_t)iB0 * 4);
    f32x4 sB1 = *reinterpret_cast<const f32x4*>(segsum + (size_t)iB1 * 4);
    f32x4 sB2 = *reinterpret_cast<const f32x4*>(segsum + (size_t)iB2 * 4);
    f32x4 sB3 = *reinterpret_cast<const f32x4*>(segsum + (size_t)iB3 * 4);
#pragma unroll
    for (int h = 0; h < 4; ++h) {
      wA0[h] = 0.25f * ev0[h] / (sA0[h] + 1e-16f);
      wA1[h] = 0.25f * ev1[h] / (sA1[h] + 1e-16f);
      wA2[h] = 0.25f * ev2[h] / (sA2[h] + 1e-16f);
      wA3[h] = 0.25f * ev3[h] / (sA3[h] + 1e-16f);
      wB0[h] = 0.25f * fv0[h] / (sB0[h] + 1e-16f);
      wB1[h] = 0.25f * fv1[h] / (sB1[h] + 1e-16f);
      wB2[h] = 0.25f * fv2[h] / (sB2[h] + 1e-16f);
      wB3[h] = 0.25f * fv3[h] / (sB3[h] + 1e-16f);
    }
  }

  f32x4 cA0 = {0.f,0.f,0.f,0.f}, cA1 = cA0, cA2 = cA0, cA3 = cA0;
  f32x4 cB0 = cA0, cB1 = cA0, cB2 = cA0, cB3 = cA0;   // [tq] : col d = tq*16+m

#pragma unroll
  for (int t = 0; t < 16; ++t) {
    const unsigned short* wp = wtu + (t * 16 + m) * 128 + rg * 8;
    bf16x8 bx0 = ld8(wp);
    bf16x8 bx1 = ld8(wp + 32);
    bf16x8 be0 = ld8(wp + 64);
    bf16x8 be1 = ld8(wp + 96);
    f32x4 cjA = {0.f,0.f,0.f,0.f};
    cjA = MFMA(xjA0, bx0, cjA, 0, 0, 0);
    cjA = MFMA(xjA1, bx1, cjA, 0, 0, 0);
    cjA = MFMA(eA0,  be0, cjA, 0, 0, 0);
    cjA = MFMA(eA1,  be1, cjA, 0, 0, 0);
    f32x4 cjB = {0.f,0.f,0.f,0.f};
    cjB = MFMA(xjB0, bx0, cjB, 0, 0, 0);
    cjB = MFMA(xjB1, bx1, cjB, 0, 0, 0);
    cjB = MFMA(eB0,  be0, cjB, 0, 0, 0);
    cjB = MFMA(eB1,  be1, cjB, 0, 0, 0);
    const int h = t >> 2, tq = t & 3;
    cA0[tq] = fmaf(softplusf(cjA[0]), wA0[h], cA0[tq]);
    cA1[tq] = fmaf(softplusf(cjA[1]), wA1[h], cA1[tq]);
    cA2[tq] = fmaf(softplusf(cjA[2]), wA2[h], cA2[tq]);
    cA3[tq] = fmaf(softplusf(cjA[3]), wA3[h], cA3[tq]);
    cB0[tq] = fmaf(softplusf(cjB[0]), wB0[h], cB0[tq]);
    cB1[tq] = fmaf(softplusf(cjB[1]), wB1[h], cB1[tq]);
    cB2[tq] = fmaf(softplusf(cjB[2]), wB2[h], cB2[tq]);
    cB3[tq] = fmaf(softplusf(cjB[3]), wB3[h], cB3[tq]);
  }

#pragma unroll
  for (int tq = 0; tq < 4; ++tq) {
    atomicAdd(&aggr[(size_t)iA0 * 64 + tq * 16 + m], cA0[tq]);
    atomicAdd(&aggr[(size_t)iA1 * 64 + tq * 16 + m], cA1[tq]);
    atomicAdd(&aggr[(size_t)iA2 * 64 + tq * 16 + m], cA2[tq]);
    atomicAdd(&aggr[(size_t)iA3 * 64 + tq * 16 + m], cA3[tq]);
    atomicAdd(&aggr[(size_t)iB0 * 64 + tq * 16 + m], cB0[tq]);
    atomicAdd(&aggr[(size_t)iB1 * 64 + tq * 16 + m], cB1[tq]);
    atomicAdd(&aggr[(size_t)iB2 * 64 + tq * 16 + m], cB2[tq]);
    atomicAdd(&aggr[(size_t)iB3 * 64 + tq * 16 + m], cB3[tq]);
  }
}

// ---------- pass 5: out = aggr + bias ----------
__global__ __launch_bounds__(256)
void k_final(const float* __restrict__ aggr, const float* __restrict__ bias,
             float* __restrict__ out)
{
  int t = blockIdx.x * 256 + threadIdx.x;
  out[t] = aggr[t] + bias[t & 63];
}

extern "C" void kernel_launch(void* const* d_in, const int* in_sizes, int n_in,
                              void* d_out, int out_size, void* d_ws, size_t ws_size,
                              hipStream_t stream)
{
  const float* x    = (const float*)d_in[0];
  const float* ea   = (const float*)d_in[1];
  const float* W    = (const float*)d_in[2];
  const float* att  = (const float*)d_in[3];
  const float* bias = (const float*)d_in[4];
  const float* gam  = (const float*)d_in[5];
  const float* bet  = (const float*)d_in[6];
  const unsigned* idx_raw = (const unsigned*)d_in[7];
  float* out = (float*)d_out;

  char* ws = (char*)d_ws;
  float*    alpha  = (float*)(ws + OFF_ALPHA);
  float*    segsum = (float*)(ws + OFF_SEGSUM);
  float*    bnst   = (float*)(ws + OFF_BN);
  unsigned* flag   = (unsigned*)(ws + OFF_BN + 64);
  float*    aggr   = (float*)(ws + OFF_AGGR);
  int*      idx    = (int*)(ws + OFF_IDX32);
  __hip_bfloat16* wt  = (__hip_bfloat16*)(ws + OFF_WT);
  __hip_bfloat16* xb  = (__hip_bfloat16*)(ws + OFF_XB);
  __hip_bfloat16* eab = (__hip_bfloat16*)(ws + OFF_EAB);

  hipMemsetAsync(ws + OFF_SEGSUM, 0, Z_SZ, stream);
  k_wprep<<<128, 256, 0, stream>>>(W, wt);
  k_idx_detect<<<(NE + 255) / 256, 256, 0, stream>>>(idx_raw, flag);
  k_idx_cvt<<<(2 * NE) / 256, 256, 0, stream>>>(idx_raw, flag, idx);
  k_cvt_bf16<<<(NN * 64 / 4) / 256, 256, 0, stream>>>(x, (unsigned*)xb);
  k_cvt_bf16<<<(NE * 64 / 4) / 256, 256, 0, stream>>>(ea, (unsigned*)eab);

  const int NB512 = (NE + 255) / 256;   // 1563, tail-guarded per wave
  k_edge_alpha<<<NB512, 512, 0, stream>>>(xb, eab, wt, att, idx, alpha, bnst);
  k_bn_fin<<<1, 64, 0, stream>>>(bnst, gam);
  k_bn_expsum<<<(NE + 255) / 256, 256, 0, stream>>>(alpha, idx, bnst, bet, segsum);
  k_edge_aggr<<<NE / 128, 256, 0, stream>>>(xb, eab, wt, idx, alpha, segsum, aggr);
  k_final<<<(NN * 64) / 256, 256, 0, stream>>>(aggr, bias, out);
}